// Round 1
// baseline (246.938 us; speedup 1.0000x reference)
//
#include <hip/hip_runtime.h>
#include <hip/hip_bf16.h>

// Sizes for this problem instance
#define BB   2
#define SS   2048
#define HH   16
#define DM_  1024
#define DH_  64
#define NROW 4096   // BB*SS
#define NQKV 3072   // 3 * HH * DH

typedef unsigned short u16;
using short8 = __attribute__((ext_vector_type(8))) short;
using bf16x8 = __attribute__((ext_vector_type(8))) __bf16;
using f32x4  = __attribute__((ext_vector_type(4))) float;

__device__ __forceinline__ u16 f2bf(float f) {
    union { float f; unsigned u; } v; v.f = f;
    unsigned r = v.u + 0x7fffu + ((v.u >> 16) & 1u);
    return (u16)(r >> 16);
}

__device__ __forceinline__ f32x4 mfma16(bf16x8 a, bf16x8 b, f32x4 c) {
    return __builtin_amdgcn_mfma_f32_16x16x32_bf16(a, b, c, 0, 0, 0);
}

// Load an A/B fragment for mfma_f32_16x16x32_bf16 from a row-major LDS tile.
// lane l, elem j -> (row = rowOff + (l&15), k = kOff + (l>>4)*8 + j)
__device__ __forceinline__ bf16x8 fragLd(const u16* base, int rowOff, int kOff, int ld) {
    const int l = threadIdx.x & 63;
    return *(const bf16x8*)(base + (rowOff + (l & 15)) * ld + kOff + ((l >> 4) << 3));
}

// ---------------------------------------------------------------------------
// pack: fp32 -> bf16 conversions + weight transposes
// ---------------------------------------------------------------------------
__global__ void pack_kernel(const float* __restrict__ x,  const float* __restrict__ wq,
                            const float* __restrict__ wk, const float* __restrict__ wv,
                            const float* __restrict__ wo, const float* __restrict__ bq,
                            const float* __restrict__ bk, const float* __restrict__ bv,
                            u16* __restrict__ Xb, u16* __restrict__ Wt,
                            u16* __restrict__ WoT, float* __restrict__ biasQKV) {
    const int tid = blockIdx.x * 256 + threadIdx.x;
    const int nth = gridDim.x * 256;
    for (int i = tid; i < NROW * DM_; i += nth) Xb[i] = f2bf(x[i]);
    // Wt[n][m], n = mat*1024 + h*64 + d  (B^T for the QKV GEMM)
    for (int i = tid; i < NQKV * DM_; i += nth) {
        int n = i >> 10, m = i & 1023;
        int mat = n >> 10, h = (n >> 6) & 15, d = n & 63;
        const float* w = (mat == 0) ? wq : ((mat == 1) ? wk : wv);
        Wt[i] = f2bf(w[(h * DM_ + m) * DH_ + d]);
    }
    // WoT[n][k] = W_O[h][d][n],  k = h*64+d  (B^T for the output GEMM)
    for (int i = tid; i < DM_ * DM_; i += nth) {
        int n = i >> 10, k = i & 1023;
        WoT[i] = f2bf(wo[k * DM_ + n]);
    }
    for (int i = tid; i < NQKV; i += nth) {
        int mat = i >> 10, h = (i >> 6) & 15, d = i & 63;
        const float* bb = (mat == 0) ? bq : ((mat == 1) ? bk : bv);
        biasQKV[i] = bb[h * DH_ + d];
    }
}

// ---------------------------------------------------------------------------
// gemm_qkv: [4096,1024] @ [1024,3072] -> scatter to Q (scaled), K, V^T
// ---------------------------------------------------------------------------
__global__ __launch_bounds__(256)
void gemm_qkv(const u16* __restrict__ Xb, const u16* __restrict__ Wt,
              const float* __restrict__ bias, u16* __restrict__ Qs,
              u16* __restrict__ Ks, u16* __restrict__ Vt) {
    __shared__ __align__(16) u16 tA[64][72];
    __shared__ __align__(16) u16 tB[64][72];
    const int brow = blockIdx.x * 64, bcol = blockIdx.y * 64;
    const int t = threadIdx.x, wid = t >> 6, l = t & 63;
    const int wr = (wid >> 1) * 32, wc = (wid & 1) * 32;
    const int sr = t >> 3, sc = (t & 7) * 8;
    f32x4 acc[2][2] = {};
    for (int k0 = 0; k0 < DM_; k0 += 64) {
        *(short8*)&tA[sr][sc]      = *(const short8*)&Xb[(brow + sr) * DM_ + k0 + sc];
        *(short8*)&tA[sr + 32][sc] = *(const short8*)&Xb[(brow + sr + 32) * DM_ + k0 + sc];
        *(short8*)&tB[sr][sc]      = *(const short8*)&Wt[(bcol + sr) * DM_ + k0 + sc];
        *(short8*)&tB[sr + 32][sc] = *(const short8*)&Wt[(bcol + sr + 32) * DM_ + k0 + sc];
        __syncthreads();
        for (int kc = 0; kc < 64; kc += 32) {
            bf16x8 a0 = fragLd(&tA[0][0], wr,      kc, 72);
            bf16x8 a1 = fragLd(&tA[0][0], wr + 16, kc, 72);
            bf16x8 b0 = fragLd(&tB[0][0], wc,      kc, 72);
            bf16x8 b1 = fragLd(&tB[0][0], wc + 16, kc, 72);
            acc[0][0] = mfma16(a0, b0, acc[0][0]);
            acc[0][1] = mfma16(a0, b1, acc[0][1]);
            acc[1][0] = mfma16(a1, b0, acc[1][0]);
            acc[1][1] = mfma16(a1, b1, acc[1][1]);
        }
        __syncthreads();
    }
    for (int i = 0; i < 2; ++i)
        for (int j = 0; j < 2; ++j)
            for (int r = 0; r < 4; ++r) {
                int row = brow + wr + i * 16 + ((l >> 4) << 2) + r;
                int col = bcol + wc + j * 16 + (l & 15);
                float v = acc[i][j][r] + bias[col];
                int mat = col >> 10, h = (col >> 6) & 15, d = col & 63;
                int b = row >> 11, s = row & 2047;
                int bh = b * HH + h;
                if (mat == 0)      Qs[(bh * SS + s) * DH_ + d] = f2bf(v * 0.125f);
                else if (mat == 1) Ks[(bh * SS + s) * DH_ + d] = f2bf(v);
                else               Vt[(bh * DH_ + d) * SS + s] = f2bf(v);
            }
}

// ---------------------------------------------------------------------------
// attn: flash attention, one (b,h,q-tile of 64) per block, 4 waves
// ---------------------------------------------------------------------------
__global__ __launch_bounds__(256)
void attn_fwd(const u16* __restrict__ Qs, const u16* __restrict__ Ks,
              const u16* __restrict__ Vt, u16* __restrict__ Zb) {
    __shared__ __align__(16) u16 tQ[64][72];
    __shared__ __align__(16) u16 tK[64][72];
    __shared__ __align__(16) u16 tV[64][72];
    __shared__ __align__(16) u16 tP[4][16][72];
    const int bh = blockIdx.y;
    const int b = bh >> 4, h = bh & 15;
    const int q0 = blockIdx.x * 64;
    const u16* Qp = Qs + bh * (SS * DH_);
    const u16* Kp = Ks + bh * (SS * DH_);
    const u16* Vp = Vt + bh * (DH_ * SS);
    const int t = threadIdx.x, wid = t >> 6, l = t & 63;
    const int sr = t >> 3, sc = (t & 7) * 8;

    *(short8*)&tQ[sr][sc]      = *(const short8*)&Qp[(q0 + sr) * DH_ + sc];
    *(short8*)&tQ[sr + 32][sc] = *(const short8*)&Qp[(q0 + sr + 32) * DH_ + sc];
    __syncthreads();
    bf16x8 aq0 = fragLd(&tQ[0][0], wid * 16, 0, 72);
    bf16x8 aq1 = fragLd(&tQ[0][0], wid * 16, 32, 72);

    float mrow[4] = {-1e30f, -1e30f, -1e30f, -1e30f};
    float lrow[4] = {0.f, 0.f, 0.f, 0.f};
    f32x4 o[4] = {};

    const int nkt = blockIdx.x;  // visit k-tiles 0..nkt (causal)
    for (int kt = 0; kt <= nkt; ++kt) {
        const int kv0 = kt * 64;
        __syncthreads();  // protect tK/tV from prior iteration's readers
        *(short8*)&tK[sr][sc]      = *(const short8*)&Kp[(kv0 + sr) * DH_ + sc];
        *(short8*)&tK[sr + 32][sc] = *(const short8*)&Kp[(kv0 + sr + 32) * DH_ + sc];
        *(short8*)&tV[sr][sc]      = *(const short8*)&Vp[sr * SS + kv0 + sc];
        *(short8*)&tV[sr + 32][sc] = *(const short8*)&Vp[(sr + 32) * SS + kv0 + sc];
        __syncthreads();

        f32x4 s[4] = {};
        for (int j = 0; j < 4; ++j) {
            s[j] = mfma16(aq0, fragLd(&tK[0][0], j * 16, 0,  72), s[j]);
            s[j] = mfma16(aq1, fragLd(&tK[0][0], j * 16, 32, 72), s[j]);
        }
        if (kt == nkt) {  // diagonal tile: causal mask (kv0 == q0 here)
            for (int j = 0; j < 4; ++j)
                for (int r = 0; r < 4; ++r) {
                    int qr = wid * 16 + ((l >> 4) << 2) + r;
                    int kc = j * 16 + (l & 15);
                    if (kc > qr) s[j][r] = -1e30f;
                }
        }
        float pr[4][4];
        for (int r = 0; r < 4; ++r) {
            float rm = fmaxf(fmaxf(s[0][r], s[1][r]), fmaxf(s[2][r], s[3][r]));
            for (int msk = 1; msk < 16; msk <<= 1) rm = fmaxf(rm, __shfl_xor(rm, msk));
            float mn  = fmaxf(mrow[r], rm);
            float scl = __expf(mrow[r] - mn);
            mrow[r] = mn;
            float rs = 0.f;
            for (int j = 0; j < 4; ++j) { float p = __expf(s[j][r] - mn); pr[j][r] = p; rs += p; }
            for (int msk = 1; msk < 16; msk <<= 1) rs += __shfl_xor(rs, msk);
            lrow[r] = lrow[r] * scl + rs;
            for (int jd = 0; jd < 4; ++jd) o[jd][r] *= scl;
        }
        // P -> per-wave LDS (repack D-layout -> A-layout), then PV
        for (int j = 0; j < 4; ++j)
            for (int r = 0; r < 4; ++r)
                tP[wid][((l >> 4) << 2) + r][j * 16 + (l & 15)] = f2bf(pr[j][r]);
        bf16x8 ap0 = fragLd(&tP[wid][0][0], 0, 0,  72);
        bf16x8 ap1 = fragLd(&tP[wid][0][0], 0, 32, 72);
        for (int jd = 0; jd < 4; ++jd) {
            o[jd] = mfma16(ap0, fragLd(&tV[0][0], jd * 16, 0,  72), o[jd]);
            o[jd] = mfma16(ap1, fragLd(&tV[0][0], jd * 16, 32, 72), o[jd]);
        }
    }
    for (int r = 0; r < 4; ++r) {
        float inv = 1.0f / lrow[r];
        int q = q0 + wid * 16 + ((l >> 4) << 2) + r;
        for (int jd = 0; jd < 4; ++jd) {
            int d = jd * 16 + (l & 15);
            Zb[((b * SS + q) * HH + h) * DH_ + d] = f2bf(o[jd][r] * inv);
        }
    }
}

// ---------------------------------------------------------------------------
// gemm_out: [4096,1024] @ [1024,1024] + b_O -> fp32 out
// ---------------------------------------------------------------------------
__global__ __launch_bounds__(256)
void gemm_out(const u16* __restrict__ Zb, const u16* __restrict__ WoT,
              const float* __restrict__ bO, float* __restrict__ out) {
    __shared__ __align__(16) u16 tA[64][72];
    __shared__ __align__(16) u16 tB[64][72];
    const int brow = blockIdx.x * 64, bcol = blockIdx.y * 64;
    const int t = threadIdx.x, wid = t >> 6, l = t & 63;
    const int wr = (wid >> 1) * 32, wc = (wid & 1) * 32;
    const int sr = t >> 3, sc = (t & 7) * 8;
    f32x4 acc[2][2] = {};
    for (int k0 = 0; k0 < DM_; k0 += 64) {
        *(short8*)&tA[sr][sc]      = *(const short8*)&Zb[(brow + sr) * DM_ + k0 + sc];
        *(short8*)&tA[sr + 32][sc] = *(const short8*)&Zb[(brow + sr + 32) * DM_ + k0 + sc];
        *(short8*)&tB[sr][sc]      = *(const short8*)&WoT[(bcol + sr) * DM_ + k0 + sc];
        *(short8*)&tB[sr + 32][sc] = *(const short8*)&WoT[(bcol + sr + 32) * DM_ + k0 + sc];
        __syncthreads();
        for (int kc = 0; kc < 64; kc += 32) {
            bf16x8 a0 = fragLd(&tA[0][0], wr,      kc, 72);
            bf16x8 a1 = fragLd(&tA[0][0], wr + 16, kc, 72);
            bf16x8 b0 = fragLd(&tB[0][0], wc,      kc, 72);
            bf16x8 b1 = fragLd(&tB[0][0], wc + 16, kc, 72);
            acc[0][0] = mfma16(a0, b0, acc[0][0]);
            acc[0][1] = mfma16(a0, b1, acc[0][1]);
            acc[1][0] = mfma16(a1, b0, acc[1][0]);
            acc[1][1] = mfma16(a1, b1, acc[1][1]);
        }
        __syncthreads();
    }
    for (int i = 0; i < 2; ++i)
        for (int j = 0; j < 2; ++j)
            for (int r = 0; r < 4; ++r) {
                int row = brow + wr + i * 16 + ((l >> 4) << 2) + r;
                int col = bcol + wc + j * 16 + (l & 15);
                out[row * DM_ + col] = acc[i][j][r] + bO[col];
            }
}

// ---------------------------------------------------------------------------
extern "C" void kernel_launch(void* const* d_in, const int* in_sizes, int n_in,
                              void* d_out, int out_size, void* d_ws, size_t ws_size,
                              hipStream_t stream) {
    const float* x  = (const float*)d_in[0];
    const float* wq = (const float*)d_in[1];
    const float* wk = (const float*)d_in[2];
    const float* wv = (const float*)d_in[3];
    const float* wo = (const float*)d_in[4];
    const float* bq = (const float*)d_in[5];
    const float* bk = (const float*)d_in[6];
    const float* bv = (const float*)d_in[7];
    const float* bO = (const float*)d_in[8];
    float* out = (float*)d_out;

    char* w = (char*)d_ws;
    u16* Xb  = (u16*)w;  w += (size_t)NROW * DM_ * 2;
    u16* Wt  = (u16*)w;  w += (size_t)NQKV * DM_ * 2;
    u16* WoT = (u16*)w;  w += (size_t)DM_ * DM_ * 2;
    float* biasQKV = (float*)w; w += (size_t)NQKV * 4;
    u16* Qs  = (u16*)w;  w += (size_t)BB * HH * SS * DH_ * 2;
    u16* Ks  = (u16*)w;  w += (size_t)BB * HH * SS * DH_ * 2;
    u16* Vt  = (u16*)w;  w += (size_t)BB * HH * SS * DH_ * 2;
    u16* Zb  = (u16*)w;  w += (size_t)BB * HH * SS * DH_ * 2;

    pack_kernel<<<1024, 256, 0, stream>>>(x, wq, wk, wv, wo, bq, bk, bv,
                                          Xb, Wt, WoT, biasQKV);
    gemm_qkv<<<dim3(NROW / 64, NQKV / 64), 256, 0, stream>>>(Xb, Wt, biasQKV, Qs, Ks, Vt);
    attn_fwd<<<dim3(SS / 64, BB * HH), 256, 0, stream>>>(Qs, Ks, Vt, Zb);
    gemm_out<<<dim3(NROW / 64, DM_ / 64), 256, 0, stream>>>(Zb, WoT, bO, out);
}

// Round 2
// 190.713 us; speedup vs baseline: 1.2948x; 1.2948x over previous
//
#include <hip/hip_runtime.h>
#include <hip/hip_bf16.h>

// Sizes for this problem instance
#define BB   2
#define SS   2048
#define HH   16
#define DM_  1024
#define DH_  64
#define NROW 4096   // BB*SS
#define NQKV 3072   // 3 * HH * DH

typedef unsigned short u16;
using short8 = __attribute__((ext_vector_type(8))) short;
using bf16x8 = __attribute__((ext_vector_type(8))) __bf16;
using f32x4  = __attribute__((ext_vector_type(4))) float;

__device__ __forceinline__ u16 f2bf(float f) {
    union { float f; unsigned u; } v; v.f = f;
    unsigned r = v.u + 0x7fffu + ((v.u >> 16) & 1u);
    return (u16)(r >> 16);
}

__device__ __forceinline__ f32x4 mfma16(bf16x8 a, bf16x8 b, f32x4 c) {
    return __builtin_amdgcn_mfma_f32_16x16x32_bf16(a, b, c, 0, 0, 0);
}

// Load an A/B fragment for mfma_f32_16x16x32_bf16 from a row-major LDS tile.
// lane l, elem j -> (row = rowOff + (l&15), k = kOff + (l>>4)*8 + j)
__device__ __forceinline__ bf16x8 fragLd(const u16* base, int rowOff, int kOff, int ld) {
    const int l = threadIdx.x & 63;
    return *(const bf16x8*)(base + (rowOff + (l & 15)) * ld + kOff + ((l >> 4) << 3));
}

// async global->LDS, 16B per lane (dest = wave-uniform base + lane*16)
__device__ __forceinline__ void gload16(const void* g, void* l) {
    __builtin_amdgcn_global_load_lds(
        (const __attribute__((address_space(1))) void*)g,
        (__attribute__((address_space(3))) void*)l, 16, 0, 0);
}

// ---------------------------------------------------------------------------
// pack: fp32 -> bf16 conversions + weight transposes
// ---------------------------------------------------------------------------
__global__ void pack_kernel(const float* __restrict__ x,  const float* __restrict__ wq,
                            const float* __restrict__ wk, const float* __restrict__ wv,
                            const float* __restrict__ wo, const float* __restrict__ bq,
                            const float* __restrict__ bk, const float* __restrict__ bv,
                            u16* __restrict__ Xb, u16* __restrict__ Wt,
                            u16* __restrict__ WoT, float* __restrict__ biasQKV) {
    const int tid = blockIdx.x * 256 + threadIdx.x;
    const int nth = gridDim.x * 256;
    for (int i = tid; i < NROW * DM_; i += nth) Xb[i] = f2bf(x[i]);
    // Wt[n][m], n = mat*1024 + h*64 + d  (B^T for the QKV GEMM)
    for (int i = tid; i < NQKV * DM_; i += nth) {
        int n = i >> 10, m = i & 1023;
        int mat = n >> 10, h = (n >> 6) & 15, d = n & 63;
        const float* w = (mat == 0) ? wq : ((mat == 1) ? wk : wv);
        Wt[i] = f2bf(w[(h * DM_ + m) * DH_ + d]);
    }
    // WoT[n][k] = W_O[h][d][n],  k = h*64+d  (B^T for the output GEMM)
    for (int i = tid; i < DM_ * DM_; i += nth) {
        int n = i >> 10, k = i & 1023;
        WoT[i] = f2bf(wo[k * DM_ + n]);
    }
    for (int i = tid; i < NQKV; i += nth) {
        int mat = i >> 10, h = (i >> 6) & 15, d = i & 63;
        const float* bb = (mat == 0) ? bq : ((mat == 1) ? bk : bv);
        biasQKV[i] = bb[h * DH_ + d];
    }
}

// ---------------------------------------------------------------------------
// gemm_qkv: m97-structure 128x128 tile. [4096,1024] @ [1024,3072]
//           -> scatter to Q (scaled), K, V^T
// ---------------------------------------------------------------------------
__global__ __launch_bounds__(256)
void gemm_qkv(const u16* __restrict__ Xb, const u16* __restrict__ Wt,
              const float* __restrict__ bias, u16* __restrict__ Qs,
              u16* __restrict__ Ks, u16* __restrict__ Vt) {
    __shared__ __align__(16) u16 tA[128 * 64];   // [128][64] linear (global_load_lds)
    __shared__ __align__(16) u16 tB[128 * 64];
    const int brow = blockIdx.x * 128, bcol = blockIdx.y * 128;
    const int t = threadIdx.x, wid = t >> 6, l = t & 63;
    const int wr = (wid >> 1) * 64, wc = (wid & 1) * 64;
    f32x4 acc[4][4] = {};
    for (int k0 = 0; k0 < DM_; k0 += 64) {
        __syncthreads();  // readers of previous tile done
        #pragma unroll
        for (int i = 0; i < 4; ++i) {
            const int off = i * 4096 + t * 16;       // byte offset in tile
            const int row = off >> 7, colB = off & 127;
            gload16((const char*)Xb + ((size_t)(brow + row) * DM_ + k0) * 2 + colB,
                    (char*)tA + off);
            gload16((const char*)Wt + ((size_t)(bcol + row) * DM_ + k0) * 2 + colB,
                    (char*)tB + off);
        }
        __syncthreads();  // drains vmcnt -> staged data visible
        #pragma unroll
        for (int kc = 0; kc < 64; kc += 32) {
            bf16x8 a[4], b[4];
            #pragma unroll
            for (int i = 0; i < 4; ++i) a[i] = fragLd(tA, wr + i * 16, kc, 64);
            #pragma unroll
            for (int j = 0; j < 4; ++j) b[j] = fragLd(tB, wc + j * 16, kc, 64);
            #pragma unroll
            for (int i = 0; i < 4; ++i)
                #pragma unroll
                for (int j = 0; j < 4; ++j)
                    acc[i][j] = mfma16(a[i], b[j], acc[i][j]);
        }
    }
    #pragma unroll
    for (int i = 0; i < 4; ++i)
        #pragma unroll
        for (int j = 0; j < 4; ++j)
            #pragma unroll
            for (int r = 0; r < 4; ++r) {
                int row = brow + wr + i * 16 + ((l >> 4) << 2) + r;
                int col = bcol + wc + j * 16 + (l & 15);
                float v = acc[i][j][r] + bias[col];
                int mat = col >> 10, h = (col >> 6) & 15, d = col & 63;
                int b = row >> 11, s = row & 2047;
                int bh = b * HH + h;
                if (mat == 0)      Qs[((size_t)bh * SS + s) * DH_ + d] = f2bf(v * 0.125f);
                else if (mat == 1) Ks[((size_t)bh * SS + s) * DH_ + d] = f2bf(v);
                else               Vt[((size_t)bh * DH_ + d) * SS + s] = f2bf(v);
            }
}

// ---------------------------------------------------------------------------
// attn: flash attention. 8 waves / 512 threads, q-tile = 128 rows.
// Causal load balance: block x handles q-tiles x and 15-x -> every block
// does exactly 34 k-tile iterations.
// ---------------------------------------------------------------------------
__global__ __launch_bounds__(512)
void attn_fwd(const u16* __restrict__ Qs, const u16* __restrict__ Ks,
              const u16* __restrict__ Vt, u16* __restrict__ Zb) {
    __shared__ __align__(16) u16 tK[64][72];
    __shared__ __align__(16) u16 tV[64][72];
    __shared__ __align__(16) u16 tP[8][16][72];
    const int bh = blockIdx.y, b = bh >> 4, h = bh & 15;
    const int t = threadIdx.x, wid = t >> 6, l = t & 63;
    const u16* Qp = Qs + (size_t)bh * SS * DH_;
    const u16* Kp = Ks + (size_t)bh * SS * DH_;
    const u16* Vp = Vt + (size_t)bh * DH_ * SS;

    for (int ph = 0; ph < 2; ++ph) {
        const int qt = ph ? (15 - blockIdx.x) : blockIdx.x;
        const int q0 = qt * 128;
        const int qw = q0 + wid * 16;   // this wave's first q row
        // Q fragments straight from global (2 x 16B per lane)
        bf16x8 aq0 = *(const bf16x8*)&Qp[(size_t)(qw + (l & 15)) * DH_ + ((l >> 4) << 3)];
        bf16x8 aq1 = *(const bf16x8*)&Qp[(size_t)(qw + (l & 15)) * DH_ + 32 + ((l >> 4) << 3)];

        float mrow[4] = {-1e30f, -1e30f, -1e30f, -1e30f};
        float lrow[4] = {0.f, 0.f, 0.f, 0.f};
        f32x4 o[4] = {};

        const int nkt = 2 * qt + 1;
        for (int kt = 0; kt <= nkt; ++kt) {
            const int kv0 = kt * 64;
            __syncthreads();   // previous tile's readers done
            {   // stage K (k-major) and V^T (d-major): one short8 per thread each
                const int rr = t >> 3, cc = (t & 7) * 8;
                *(short8*)&tK[rr][cc] = *(const short8*)&Kp[(size_t)(kv0 + rr) * DH_ + cc];
                *(short8*)&tV[rr][cc] = *(const short8*)&Vp[(size_t)rr * SS + kv0 + cc];
            }
            __syncthreads();
            if (kv0 <= qw + 15) {   // wave has unmasked work in this k-tile
                f32x4 s[4] = {};
                #pragma unroll
                for (int j = 0; j < 4; ++j) {
                    s[j] = mfma16(aq0, fragLd(&tK[0][0], j * 16, 0,  72), s[j]);
                    s[j] = mfma16(aq1, fragLd(&tK[0][0], j * 16, 32, 72), s[j]);
                }
                if (kv0 + 63 > qw) {   // diagonal overlap: causal mask
                    #pragma unroll
                    for (int j = 0; j < 4; ++j)
                        #pragma unroll
                        for (int r = 0; r < 4; ++r) {
                            int qr = qw + ((l >> 4) << 2) + r;
                            int kc = kv0 + j * 16 + (l & 15);
                            if (kc > qr) s[j][r] = -1e30f;
                        }
                }
                float pr[4][4];
                #pragma unroll
                for (int r = 0; r < 4; ++r) {
                    float rm = fmaxf(fmaxf(s[0][r], s[1][r]), fmaxf(s[2][r], s[3][r]));
                    #pragma unroll
                    for (int msk = 1; msk < 16; msk <<= 1) rm = fmaxf(rm, __shfl_xor(rm, msk));
                    float mn  = fmaxf(mrow[r], rm);
                    float scl = __expf(mrow[r] - mn);
                    mrow[r] = mn;
                    float rs = 0.f;
                    #pragma unroll
                    for (int j = 0; j < 4; ++j) {
                        float p = __expf(s[j][r] - mn); pr[j][r] = p; rs += p;
                    }
                    #pragma unroll
                    for (int msk = 1; msk < 16; msk <<= 1) rs += __shfl_xor(rs, msk);
                    lrow[r] = lrow[r] * scl + rs;
                    #pragma unroll
                    for (int jd = 0; jd < 4; ++jd) o[jd][r] *= scl;
                }
                // P -> per-wave LDS (D-layout -> A-layout), then PV
                #pragma unroll
                for (int j = 0; j < 4; ++j)
                    #pragma unroll
                    for (int r = 0; r < 4; ++r)
                        tP[wid][((l >> 4) << 2) + r][j * 16 + (l & 15)] = f2bf(pr[j][r]);
                bf16x8 ap0 = fragLd(&tP[wid][0][0], 0, 0,  72);
                bf16x8 ap1 = fragLd(&tP[wid][0][0], 0, 32, 72);
                #pragma unroll
                for (int jd = 0; jd < 4; ++jd) {
                    o[jd] = mfma16(ap0, fragLd(&tV[0][0], jd * 16, 0,  72), o[jd]);
                    o[jd] = mfma16(ap1, fragLd(&tV[0][0], jd * 16, 32, 72), o[jd]);
                }
            }
        }
        #pragma unroll
        for (int r = 0; r < 4; ++r) {
            float inv = 1.0f / lrow[r];
            int q = qw + ((l >> 4) << 2) + r;
            #pragma unroll
            for (int jd = 0; jd < 4; ++jd) {
                int d = jd * 16 + (l & 15);
                Zb[(((size_t)b * SS + q) * HH + h) * DH_ + d] = f2bf(o[jd][r] * inv);
            }
        }
    }
}

// ---------------------------------------------------------------------------
// gemm_out: m97-structure 128x128 tile. [4096,1024] @ [1024,1024] + b_O -> fp32
// ---------------------------------------------------------------------------
__global__ __launch_bounds__(256)
void gemm_out(const u16* __restrict__ Zb, const u16* __restrict__ WoT,
              const float* __restrict__ bO, float* __restrict__ out) {
    __shared__ __align__(16) u16 tA[128 * 64];
    __shared__ __align__(16) u16 tB[128 * 64];
    const int brow = blockIdx.x * 128, bcol = blockIdx.y * 128;
    const int t = threadIdx.x, wid = t >> 6, l = t & 63;
    const int wr = (wid >> 1) * 64, wc = (wid & 1) * 64;
    f32x4 acc[4][4] = {};
    for (int k0 = 0; k0 < DM_; k0 += 64) {
        __syncthreads();
        #pragma unroll
        for (int i = 0; i < 4; ++i) {
            const int off = i * 4096 + t * 16;
            const int row = off >> 7, colB = off & 127;
            gload16((const char*)Zb + ((size_t)(brow + row) * DM_ + k0) * 2 + colB,
                    (char*)tA + off);
            gload16((const char*)WoT + ((size_t)(bcol + row) * DM_ + k0) * 2 + colB,
                    (char*)tB + off);
        }
        __syncthreads();
        #pragma unroll
        for (int kc = 0; kc < 64; kc += 32) {
            bf16x8 a[4], b[4];
            #pragma unroll
            for (int i = 0; i < 4; ++i) a[i] = fragLd(tA, wr + i * 16, kc, 64);
            #pragma unroll
            for (int j = 0; j < 4; ++j) b[j] = fragLd(tB, wc + j * 16, kc, 64);
            #pragma unroll
            for (int i = 0; i < 4; ++i)
                #pragma unroll
                for (int j = 0; j < 4; ++j)
                    acc[i][j] = mfma16(a[i], b[j], acc[i][j]);
        }
    }
    #pragma unroll
    for (int i = 0; i < 4; ++i)
        #pragma unroll
        for (int j = 0; j < 4; ++j)
            #pragma unroll
            for (int r = 0; r < 4; ++r) {
                int row = brow + wr + i * 16 + ((l >> 4) << 2) + r;
                int col = bcol + wc + j * 16 + (l & 15);
                out[(size_t)row * DM_ + col] = acc[i][j][r] + bO[col];
            }
}

// ---------------------------------------------------------------------------
extern "C" void kernel_launch(void* const* d_in, const int* in_sizes, int n_in,
                              void* d_out, int out_size, void* d_ws, size_t ws_size,
                              hipStream_t stream) {
    const float* x  = (const float*)d_in[0];
    const float* wq = (const float*)d_in[1];
    const float* wk = (const float*)d_in[2];
    const float* wv = (const float*)d_in[3];
    const float* wo = (const float*)d_in[4];
    const float* bq = (const float*)d_in[5];
    const float* bk = (const float*)d_in[6];
    const float* bv = (const float*)d_in[7];
    const float* bO = (const float*)d_in[8];
    float* out = (float*)d_out;

    char* w = (char*)d_ws;
    u16* Xb  = (u16*)w;  w += (size_t)NROW * DM_ * 2;
    u16* Wt  = (u16*)w;  w += (size_t)NQKV * DM_ * 2;
    u16* WoT = (u16*)w;  w += (size_t)DM_ * DM_ * 2;
    float* biasQKV = (float*)w; w += (size_t)NQKV * 4;
    u16* Qs  = (u16*)w;  w += (size_t)BB * HH * SS * DH_ * 2;
    u16* Ks  = (u16*)w;  w += (size_t)BB * HH * SS * DH_ * 2;
    u16* Vt  = (u16*)w;  w += (size_t)BB * HH * SS * DH_ * 2;
    u16* Zb  = (u16*)w;  w += (size_t)BB * HH * SS * DH_ * 2;

    pack_kernel<<<1024, 256, 0, stream>>>(x, wq, wk, wv, wo, bq, bk, bv,
                                          Xb, Wt, WoT, biasQKV);
    gemm_qkv<<<dim3(NROW / 128, NQKV / 128), 256, 0, stream>>>(Xb, Wt, biasQKV, Qs, Ks, Vt);
    attn_fwd<<<dim3(SS / 256, BB * HH), 512, 0, stream>>>(Qs, Ks, Vt, Zb);
    gemm_out<<<dim3(NROW / 128, DM_ / 128), 256, 0, stream>>>(Zb, WoT, bO, out);
}

// Round 3
// 169.266 us; speedup vs baseline: 1.4589x; 1.1267x over previous
//
#include <hip/hip_runtime.h>
#include <hip/hip_bf16.h>

// Sizes for this problem instance
#define BB   2
#define SS   2048
#define HH   16
#define DM_  1024
#define DH_  64
#define NROW 4096   // BB*SS
#define NQKV 3072   // 3 * HH * DH

typedef unsigned short u16;
using short8 = __attribute__((ext_vector_type(8))) short;
using bf16x8 = __attribute__((ext_vector_type(8))) __bf16;
using f32x4  = __attribute__((ext_vector_type(4))) float;

__device__ __forceinline__ u16 f2bf(float f) {
    union { float f; unsigned u; } v; v.f = f;
    unsigned r = v.u + 0x7fffu + ((v.u >> 16) & 1u);
    return (u16)(r >> 16);
}

__device__ __forceinline__ f32x4 mfma16(bf16x8 a, bf16x8 b, f32x4 c) {
    return __builtin_amdgcn_mfma_f32_16x16x32_bf16(a, b, c, 0, 0, 0);
}

// Load an A/B fragment for mfma_f32_16x16x32_bf16 from a row-major LDS tile.
// lane l, elem j -> (row = rowOff + (l&15), k = kOff + (l>>4)*8 + j)
__device__ __forceinline__ bf16x8 fragLd(const u16* base, int rowOff, int kOff, int ld) {
    const int l = threadIdx.x & 63;
    return *(const bf16x8*)(base + (rowOff + (l & 15)) * ld + kOff + ((l >> 4) << 3));
}

// async global->LDS, 16B per lane (dest = wave-uniform base + lane*16)
__device__ __forceinline__ void gload16(const void* g, void* l) {
    __builtin_amdgcn_global_load_lds(
        (const __attribute__((address_space(1))) void*)g,
        (__attribute__((address_space(3))) void*)l, 16, 0, 0);
}

// ---------------------------------------------------------------------------
// pack: fp32 -> bf16 conversions + weight transposes
// ---------------------------------------------------------------------------
__global__ void pack_kernel(const float* __restrict__ x,  const float* __restrict__ wq,
                            const float* __restrict__ wk, const float* __restrict__ wv,
                            const float* __restrict__ wo, const float* __restrict__ bq,
                            const float* __restrict__ bk, const float* __restrict__ bv,
                            u16* __restrict__ Xb, u16* __restrict__ Wt,
                            u16* __restrict__ WoT, float* __restrict__ biasQKV) {
    const int tid = blockIdx.x * 256 + threadIdx.x;
    const int nth = gridDim.x * 256;
    for (int i = tid; i < NROW * DM_; i += nth) Xb[i] = f2bf(x[i]);
    // Wt[n][m], n = mat*1024 + h*64 + d  (B^T for the QKV GEMM)
    for (int i = tid; i < NQKV * DM_; i += nth) {
        int n = i >> 10, m = i & 1023;
        int mat = n >> 10, h = (n >> 6) & 15, d = n & 63;
        const float* w = (mat == 0) ? wq : ((mat == 1) ? wk : wv);
        Wt[i] = f2bf(w[(h * DM_ + m) * DH_ + d]);
    }
    // WoT[n][k] = W_O[h][d][n],  k = h*64+d  (B^T for the output GEMM)
    for (int i = tid; i < DM_ * DM_; i += nth) {
        int n = i >> 10, k = i & 1023;
        WoT[i] = f2bf(wo[k * DM_ + n]);
    }
    for (int i = tid; i < NQKV; i += nth) {
        int mat = i >> 10, h = (i >> 6) & 15, d = i & 63;
        const float* bb = (mat == 0) ? bq : ((mat == 1) ? bk : bv);
        biasQKV[i] = bb[h * DH_ + d];
    }
}

// ---------------------------------------------------------------------------
// gemm_qkv: m97-structure 128x128 tile. [4096,1024] @ [1024,3072]
//           -> scatter to Q (scaled), K, V^T
// ---------------------------------------------------------------------------
__global__ __launch_bounds__(256)
void gemm_qkv(const u16* __restrict__ Xb, const u16* __restrict__ Wt,
              const float* __restrict__ bias, u16* __restrict__ Qs,
              u16* __restrict__ Ks, u16* __restrict__ Vt) {
    __shared__ __align__(16) u16 tA[128 * 64];   // [128][64] linear (global_load_lds)
    __shared__ __align__(16) u16 tB[128 * 64];
    const int brow = blockIdx.x * 128, bcol = blockIdx.y * 128;
    const int t = threadIdx.x, wid = t >> 6, l = t & 63;
    const int wr = (wid >> 1) * 64, wc = (wid & 1) * 64;
    f32x4 acc[4][4] = {};
    for (int k0 = 0; k0 < DM_; k0 += 64) {
        __syncthreads();  // readers of previous tile done
        #pragma unroll
        for (int i = 0; i < 4; ++i) {
            const int off = i * 4096 + t * 16;       // byte offset in tile
            const int row = off >> 7, colB = off & 127;
            gload16((const char*)Xb + ((size_t)(brow + row) * DM_ + k0) * 2 + colB,
                    (char*)tA + off);
            gload16((const char*)Wt + ((size_t)(bcol + row) * DM_ + k0) * 2 + colB,
                    (char*)tB + off);
        }
        __syncthreads();  // drains vmcnt -> staged data visible
        #pragma unroll
        for (int kc = 0; kc < 64; kc += 32) {
            bf16x8 a[4], b[4];
            #pragma unroll
            for (int i = 0; i < 4; ++i) a[i] = fragLd(tA, wr + i * 16, kc, 64);
            #pragma unroll
            for (int j = 0; j < 4; ++j) b[j] = fragLd(tB, wc + j * 16, kc, 64);
            #pragma unroll
            for (int i = 0; i < 4; ++i)
                #pragma unroll
                for (int j = 0; j < 4; ++j)
                    acc[i][j] = mfma16(a[i], b[j], acc[i][j]);
        }
    }
    #pragma unroll
    for (int i = 0; i < 4; ++i)
        #pragma unroll
        for (int j = 0; j < 4; ++j)
            #pragma unroll
            for (int r = 0; r < 4; ++r) {
                int row = brow + wr + i * 16 + ((l >> 4) << 2) + r;
                int col = bcol + wc + j * 16 + (l & 15);
                float v = acc[i][j][r] + bias[col];
                int mat = col >> 10, h = (col >> 6) & 15, d = col & 63;
                int b = row >> 11, s = row & 2047;
                int bh = b * HH + h;
                if (mat == 0)      Qs[((size_t)bh * SS + s) * DH_ + d] = f2bf(v * 0.125f);
                else if (mat == 1) Ks[((size_t)bh * SS + s) * DH_ + d] = f2bf(v);
                else               Vt[((size_t)bh * DH_ + d) * SS + s] = f2bf(v);
            }
}

// ---------------------------------------------------------------------------
// attn: flash attention, KVBLK=128, fragment-linear LDS (conflict-free b128),
// reg-prefetch of next K/V tile, defer-max. 8 waves, q-tile = 128 rows,
// blocks pair q-tiles (x, 15-x) -> uniform 17 x 128-wide k-tiles per block.
// ---------------------------------------------------------------------------
__global__ __launch_bounds__(512)
void attn_fwd(const u16* __restrict__ Qs, const u16* __restrict__ Ks,
              const u16* __restrict__ Vt, u16* __restrict__ Zb) {
    // fragment-linear buffers: fK[sec=jk*2+kc2][lane][8], fV[sec=jd*4+kc2][lane][8]
    __shared__ __align__(16) u16 fK[8192];    // 128 kseq x 64 d   (16 KiB)
    __shared__ __align__(16) u16 fV[8192];    // 64 d x 128 kseq   (16 KiB)
    __shared__ __align__(16) u16 fP[16384];   // per-wave 16 q x 128 kseq (32 KiB)
    const int bh = blockIdx.y, b = bh >> 4, h = bh & 15;
    const int t = threadIdx.x, wid = t >> 6, l = t & 63;
    const u16* Qp = Qs + (size_t)bh * SS * DH_;
    const u16* Kp = Ks + (size_t)bh * SS * DH_;
    const u16* Vp = Vt + (size_t)bh * DH_ * SS;

    // staging chunk addressing: thread t stages chunks c0=t, c1=t+512 of each tile
    const int c0 = t, c1 = t + 512;
    // K chunk c: row=(c>>7)*16+(c&15), d=((c>>6)&1)*32+((c>>4)&3)*8
    const int kOff0 = (((c0 >> 7) << 4) + (c0 & 15)) * DH_ + ((c0 >> 6) & 1) * 32 + ((c0 >> 4) & 3) * 8;
    const int kOff1 = (((c1 >> 7) << 4) + (c1 & 15)) * DH_ + ((c1 >> 6) & 1) * 32 + ((c1 >> 4) & 3) * 8;
    // V chunk c: d=(c>>8)*16+(c&15), ks=((c>>6)&3)*32+((c>>4)&3)*8
    const size_t vOff0 = (size_t)(((c0 >> 8) << 4) + (c0 & 15)) * SS + ((c0 >> 6) & 3) * 32 + ((c0 >> 4) & 3) * 8;
    const size_t vOff1 = (size_t)(((c1 >> 8) << 4) + (c1 & 15)) * SS + ((c1 >> 6) & 3) * 32 + ((c1 >> 4) & 3) * 8;
    u16* ldsK0 = fK + c0 * 8;  u16* ldsK1 = fK + c1 * 8;
    u16* ldsV0 = fV + c0 * 8;  u16* ldsV1 = fV + c1 * 8;
    u16* fPw = fP + wid * 2048;

    for (int ph = 0; ph < 2; ++ph) {
        const int qt = ph ? (15 - (int)blockIdx.x) : (int)blockIdx.x;
        const int q0 = qt * 128;
        const int nt = qt + 1;            // number of 128-wide k-tiles
        const int qw = q0 + wid * 16;     // wave's first q row
        bf16x8 aq0 = *(const bf16x8*)&Qp[(size_t)(qw + (l & 15)) * DH_ + ((l >> 4) << 3)];
        bf16x8 aq1 = *(const bf16x8*)&Qp[(size_t)(qw + (l & 15)) * DH_ + 32 + ((l >> 4) << 3)];

        float mrow[4] = {-1e30f, -1e30f, -1e30f, -1e30f};
        float lrow[4] = {0.f, 0.f, 0.f, 0.f};
        f32x4 o[4] = {};

        // prefetch tile 0 into registers
        short8 kA0 = *(const short8*)(Kp + kOff0);
        short8 kA1 = *(const short8*)(Kp + kOff1);
        short8 vA0 = *(const short8*)(Vp + vOff0);
        short8 vA1 = *(const short8*)(Vp + vOff1);

        for (int kt = 0; kt < nt; ++kt) {
            __syncthreads();                       // prev tile's readers done
            *(short8*)ldsK0 = kA0;  *(short8*)ldsK1 = kA1;
            *(short8*)ldsV0 = vA0;  *(short8*)ldsV1 = vA1;
            __syncthreads();                       // staged data visible
            if (kt + 1 < nt) {                     // prefetch next tile (T14)
                const int nb = (kt + 1) * 128;
                kA0 = *(const short8*)(Kp + nb * DH_ + kOff0);
                kA1 = *(const short8*)(Kp + nb * DH_ + kOff1);
                vA0 = *(const short8*)(Vp + nb + vOff0);
                vA1 = *(const short8*)(Vp + nb + vOff1);
            }
            const bool diag = (kt == nt - 1);      // last tile touches diagonal
            const int jtop = diag ? (wid | 1) : 7;
            const int ktop = diag ? (wid >> 1) : 3;

            f32x4 s[8] = {};
            #pragma unroll
            for (int jk = 0; jk < 8; ++jk) if (jk <= jtop) {
                s[jk] = mfma16(aq0, *(const bf16x8*)(fK + (jk * 2 + 0) * 512 + l * 8), s[jk]);
                s[jk] = mfma16(aq1, *(const bf16x8*)(fK + (jk * 2 + 1) * 512 + l * 8), s[jk]);
            }
            if (diag) {   // causal mask (kv0 == q0 on the diagonal tile)
                #pragma unroll
                for (int jk = 0; jk < 8; ++jk) if (jk <= jtop && jk >= wid) {
                    #pragma unroll
                    for (int r = 0; r < 4; ++r) {
                        int qr = wid * 16 + ((l >> 4) << 2) + r;
                        int kc = jk * 16 + (l & 15);
                        if (kc > qr) s[jk][r] = -1e30f;
                    }
                }
            }
            // row max
            float rm[4];
            #pragma unroll
            for (int r = 0; r < 4; ++r) {
                float m = -1e30f;
                #pragma unroll
                for (int jk = 0; jk < 8; ++jk) if (jk <= jtop) m = fmaxf(m, s[jk][r]);
                #pragma unroll
                for (int msk = 1; msk < 16; msk <<= 1) m = fmaxf(m, __shfl_xor(m, msk));
                rm[r] = m;
            }
            // defer-max: rescale only if max grew by more than THR=8
            float need = fmaxf(fmaxf(rm[0] - mrow[0], rm[1] - mrow[1]),
                               fmaxf(rm[2] - mrow[2], rm[3] - mrow[3]));
            if (!__all(need <= 8.f)) {
                #pragma unroll
                for (int r = 0; r < 4; ++r) {
                    float mn = fmaxf(mrow[r], rm[r]);
                    float scl = __expf(mrow[r] - mn);
                    mrow[r] = mn;  lrow[r] *= scl;
                    #pragma unroll
                    for (int jd = 0; jd < 4; ++jd) o[jd][r] *= scl;
                }
            }
            // exp + write P to fragment-linear LDS + row sum
            #pragma unroll
            for (int r = 0; r < 4; ++r) {
                float rs = 0.f;
                #pragma unroll
                for (int jk = 0; jk < 8; ++jk) if (jk <= jtop) {
                    float p = __expf(s[jk][r] - mrow[r]);
                    rs += p;
                    fPw[(jk >> 1) * 512 + ((jk & 1) * 2 + ((l & 15) >> 3)) * 128 +
                        (((l >> 4) << 2) + r) * 8 + (l & 7)] = f2bf(p);
                }
                #pragma unroll
                for (int msk = 1; msk < 16; msk <<= 1) rs += __shfl_xor(rs, msk);
                lrow[r] += rs;
            }
            // PV
            #pragma unroll
            for (int kc2 = 0; kc2 < 4; ++kc2) if (kc2 <= ktop) {
                bf16x8 pa = *(const bf16x8*)(fPw + kc2 * 512 + l * 8);
                #pragma unroll
                for (int jd = 0; jd < 4; ++jd)
                    o[jd] = mfma16(pa, *(const bf16x8*)(fV + (jd * 4 + kc2) * 512 + l * 8), o[jd]);
            }
        }
        #pragma unroll
        for (int r = 0; r < 4; ++r) {
            float inv = 1.0f / lrow[r];
            int q = qw + ((l >> 4) << 2) + r;
            #pragma unroll
            for (int jd = 0; jd < 4; ++jd) {
                int d = jd * 16 + (l & 15);
                Zb[(((size_t)b * SS + q) * HH + h) * DH_ + d] = f2bf(o[jd][r] * inv);
            }
        }
    }
}

// ---------------------------------------------------------------------------
// gemm_out: m97-structure 128x128 tile. [4096,1024] @ [1024,1024] + b_O -> fp32
// ---------------------------------------------------------------------------
__global__ __launch_bounds__(256)
void gemm_out(const u16* __restrict__ Zb, const u16* __restrict__ WoT,
              const float* __restrict__ bO, float* __restrict__ out) {
    __shared__ __align__(16) u16 tA[128 * 64];
    __shared__ __align__(16) u16 tB[128 * 64];
    const int brow = blockIdx.x * 128, bcol = blockIdx.y * 128;
    const int t = threadIdx.x, wid = t >> 6, l = t & 63;
    const int wr = (wid >> 1) * 64, wc = (wid & 1) * 64;
    f32x4 acc[4][4] = {};
    for (int k0 = 0; k0 < DM_; k0 += 64) {
        __syncthreads();
        #pragma unroll
        for (int i = 0; i < 4; ++i) {
            const int off = i * 4096 + t * 16;
            const int row = off >> 7, colB = off & 127;
            gload16((const char*)Zb + ((size_t)(brow + row) * DM_ + k0) * 2 + colB,
                    (char*)tA + off);
            gload16((const char*)WoT + ((size_t)(bcol + row) * DM_ + k0) * 2 + colB,
                    (char*)tB + off);
        }
        __syncthreads();
        #pragma unroll
        for (int kc = 0; kc < 64; kc += 32) {
            bf16x8 a[4], b[4];
            #pragma unroll
            for (int i = 0; i < 4; ++i) a[i] = fragLd(tA, wr + i * 16, kc, 64);
            #pragma unroll
            for (int j = 0; j < 4; ++j) b[j] = fragLd(tB, wc + j * 16, kc, 64);
            #pragma unroll
            for (int i = 0; i < 4; ++i)
                #pragma unroll
                for (int j = 0; j < 4; ++j)
                    acc[i][j] = mfma16(a[i], b[j], acc[i][j]);
        }
    }
    #pragma unroll
    for (int i = 0; i < 4; ++i)
        #pragma unroll
        for (int j = 0; j < 4; ++j)
            #pragma unroll
            for (int r = 0; r < 4; ++r) {
                int row = brow + wr + i * 16 + ((l >> 4) << 2) + r;
                int col = bcol + wc + j * 16 + (l & 15);
                out[(size_t)row * DM_ + col] = acc[i][j][r] + bO[col];
            }
}

// ---------------------------------------------------------------------------
extern "C" void kernel_launch(void* const* d_in, const int* in_sizes, int n_in,
                              void* d_out, int out_size, void* d_ws, size_t ws_size,
                              hipStream_t stream) {
    const float* x  = (const float*)d_in[0];
    const float* wq = (const float*)d_in[1];
    const float* wk = (const float*)d_in[2];
    const float* wv = (const float*)d_in[3];
    const float* wo = (const float*)d_in[4];
    const float* bq = (const float*)d_in[5];
    const float* bk = (const float*)d_in[6];
    const float* bv = (const float*)d_in[7];
    const float* bO = (const float*)d_in[8];
    float* out = (float*)d_out;

    char* w = (char*)d_ws;
    u16* Xb  = (u16*)w;  w += (size_t)NROW * DM_ * 2;
    u16* Wt  = (u16*)w;  w += (size_t)NQKV * DM_ * 2;
    u16* WoT = (u16*)w;  w += (size_t)DM_ * DM_ * 2;
    float* biasQKV = (float*)w; w += (size_t)NQKV * 4;
    u16* Qs  = (u16*)w;  w += (size_t)BB * HH * SS * DH_ * 2;
    u16* Ks  = (u16*)w;  w += (size_t)BB * HH * SS * DH_ * 2;
    u16* Vt  = (u16*)w;  w += (size_t)BB * HH * SS * DH_ * 2;
    u16* Zb  = (u16*)w;  w += (size_t)BB * HH * SS * DH_ * 2;

    pack_kernel<<<1024, 256, 0, stream>>>(x, wq, wk, wv, wo, bq, bk, bv,
                                          Xb, Wt, WoT, biasQKV);
    gemm_qkv<<<dim3(NROW / 128, NQKV / 128), 256, 0, stream>>>(Xb, Wt, biasQKV, Qs, Ks, Vt);
    attn_fwd<<<dim3(SS / 256, BB * HH), 512, 0, stream>>>(Qs, Ks, Vt, Zb);
    gemm_out<<<dim3(NROW / 128, DM_ / 128), 256, 0, stream>>>(Zb, WoT, bO, out);
}